// Round 4
// baseline (1252.920 us; speedup 1.0000x reference)
//
#include <hip/hip_runtime.h>
#include <stdint.h>

typedef __attribute__((ext_vector_type(8))) __bf16 bf16x8;
typedef __attribute__((ext_vector_type(4))) float f32x4;

__device__ __forceinline__ unsigned short f2bf(float f) {
  unsigned u = __float_as_uint(f);
  u += 0x7FFFu + ((u >> 16) & 1u);
  return (unsigned short)(u >> 16);
}
__device__ __forceinline__ float bf2f(unsigned short u) {
  return __uint_as_float((unsigned)u << 16);
}

__device__ __forceinline__ void gload16(const void* g, void* lds) {
  __builtin_amdgcn_global_load_lds((const __attribute__((address_space(1))) void*)g,
                                   (__attribute__((address_space(3))) void*)lds, 16, 0, 0);
}

// ---------------- elementwise / prep kernels ----------------

__global__ __launch_bounds__(256) void rownorm_bf16(const float* __restrict__ x,
                                                    unsigned short* __restrict__ y,
                                                    int cols) {
  const int row = blockIdx.x;
  const float4* x4 = (const float4*)(x + (size_t)row * cols);
  const int n4 = cols >> 2;
  float s = 0.f;
  for (int i = threadIdx.x; i < n4; i += 256) {
    float4 t = x4[i];
    s += t.x * t.x + t.y * t.y + t.z * t.z + t.w * t.w;
  }
#pragma unroll
  for (int o = 32; o >= 1; o >>= 1) s += __shfl_xor(s, o, 64);
  __shared__ float red[4];
  if ((threadIdx.x & 63) == 0) red[threadIdx.x >> 6] = s;
  __syncthreads();
  const float tot = red[0] + red[1] + red[2] + red[3];
  const float sc = 1.0f / sqrtf(tot + 1e-6f);
  ushort4* y4 = (ushort4*)(y + (size_t)row * cols);
  for (int i = threadIdx.x; i < n4; i += 256) {
    float4 t = x4[i];
    ushort4 o;
    o.x = f2bf(t.x * sc); o.y = f2bf(t.y * sc);
    o.z = f2bf(t.z * sc); o.w = f2bf(t.w * sc);
    y4[i] = o;
  }
}

__global__ __launch_bounds__(256) void convert_bf16(const float* __restrict__ x,
                                                    unsigned short* __restrict__ y,
                                                    long n4) {
  long i = (long)blockIdx.x * 256 + threadIdx.x;
  const long stride = (long)gridDim.x * 256;
  for (; i < n4; i += stride) {
    float4 t = ((const float4*)x)[i];
    ushort4 o;
    o.x = f2bf(t.x); o.y = f2bf(t.y); o.z = f2bf(t.z); o.w = f2bf(t.w);
    ((ushort4*)y)[i] = o;
  }
}

__global__ __launch_bounds__(256) void convert_strided_bf16(const float* __restrict__ x,
                                                            unsigned short* __restrict__ y,
                                                            int rows, int cols, int ld, int off) {
  const int c4n = cols >> 2;
  const int n4 = rows * c4n;
  for (int i = blockIdx.x * 256 + threadIdx.x; i < n4; i += gridDim.x * 256) {
    const int r = i / c4n;
    const int c4 = i - r * c4n;
    float4 t = ((const float4*)x)[i];
    ushort4 o;
    o.x = f2bf(t.x); o.y = f2bf(t.y); o.z = f2bf(t.z); o.w = f2bf(t.w);
    *(ushort4*)(y + (size_t)r * ld + off + c4 * 4) = o;
  }
}

// ---------------- sparsemax -> compact (idx, weight) lists ----------------
// one block per row; sim row is bf16. tau via 32-step bisection on [max-1,max].
// Deterministic compaction: per-thread counts -> Hillis-Steele inclusive scan.
__global__ __launch_bounds__(256) void sparsemax_compact(
    const unsigned short* __restrict__ simb, unsigned short* __restrict__ sidx,
    unsigned short* __restrict__ swv, int* __restrict__ scnt, int Mc, int cap) {
  const int row = blockIdx.x;
  const int tid = threadIdx.x;
  const ushort4* z4 = (const ushort4*)(simb + (size_t)row * Mc);
  float z[32];
#pragma unroll
  for (int i = 0; i < 8; ++i) {
    ushort4 v = z4[i * 256 + tid];
    z[i * 4 + 0] = bf2f(v.x); z[i * 4 + 1] = bf2f(v.y);
    z[i * 4 + 2] = bf2f(v.z); z[i * 4 + 3] = bf2f(v.w);
  }
  float mx = z[0];
#pragma unroll
  for (int j = 1; j < 32; ++j) mx = fmaxf(mx, z[j]);
#pragma unroll
  for (int o = 32; o >= 1; o >>= 1) mx = fmaxf(mx, __shfl_xor(mx, o, 64));
  __shared__ float red[4];
  const int wv = tid >> 6, ln = tid & 63;
  if (ln == 0) red[wv] = mx;
  __syncthreads();
  mx = fmaxf(fmaxf(red[0], red[1]), fmaxf(red[2], red[3]));

  float lo = mx - 1.0f, hi = mx;
  for (int it = 0; it < 32; ++it) {
    const float tau = 0.5f * (lo + hi);
    float s = 0.f;
#pragma unroll
    for (int j = 0; j < 32; ++j) s += fmaxf(z[j] - tau, 0.f);
#pragma unroll
    for (int o = 32; o >= 1; o >>= 1) s += __shfl_xor(s, o, 64);
    __syncthreads();
    if (ln == 0) red[wv] = s;
    __syncthreads();
    s = red[0] + red[1] + red[2] + red[3];
    if (s > 1.0f) lo = tau; else hi = tau;
  }
  const float tau = 0.5f * (lo + hi);

  int cnt = 0;
#pragma unroll
  for (int j = 0; j < 32; ++j) cnt += (z[j] > tau) ? 1 : 0;

  __shared__ int pw[256];
  pw[tid] = cnt;
  __syncthreads();
  for (int off = 1; off < 256; off <<= 1) {
    int v = pw[tid];
    int add = (tid >= off) ? pw[tid - off] : 0;
    __syncthreads();
    pw[tid] = v + add;
    __syncthreads();
  }
  const int total = pw[255];
  int p = pw[tid] - cnt;                 // exclusive prefix
  unsigned short* si = sidx + (size_t)row * cap;
  unsigned short* sw = swv + (size_t)row * cap;
#pragma unroll
  for (int j = 0; j < 32; ++j) {
    if (z[j] > tau) {
      if (p < cap) {
        si[p] = (unsigned short)((j >> 2) * 1024 + tid * 4 + (j & 3));
        sw[p] = f2bf(z[j] - tau);
      }
      ++p;
    }
  }
  if (tid == 0) scnt[row] = total < cap ? total : cap;
}

// ---------------- sparse mv: fin[:, D:2D) = sum_j w_j * mem[idx_j] ----------------
// one block per row; 256 threads x 8 f32 cols each (D=2048). Coalesced 8KB row reads.
__global__ __launch_bounds__(256) void mv_sparse(
    const float* __restrict__ mem, const unsigned short* __restrict__ sidx,
    const unsigned short* __restrict__ swv, const int* __restrict__ scnt,
    unsigned short* __restrict__ fin, int D, int ld, int cap) {
  const int row = blockIdx.x;
  const int tid = threadIdx.x;
  const int cnt = scnt[row];
  __shared__ unsigned short lidx[1024];
  __shared__ float lw[1024];
  for (int i = tid; i < cnt; i += 256) {
    lidx[i] = sidx[(size_t)row * cap + i];
    lw[i] = bf2f(swv[(size_t)row * cap + i]);
  }
  __syncthreads();
  float acc[8] = {};
  const int c0 = tid * 8;
  for (int j = 0; j < cnt; ++j) {
    const float w = lw[j];
    const float4* mr = (const float4*)(mem + (size_t)lidx[j] * D + c0);
    float4 a = mr[0], b = mr[1];
    acc[0] += w * a.x; acc[1] += w * a.y; acc[2] += w * a.z; acc[3] += w * a.w;
    acc[4] += w * b.x; acc[5] += w * b.y; acc[6] += w * b.z; acc[7] += w * b.w;
  }
  unsigned short* dst = fin + (size_t)row * ld + D + c0;
  ushort4 o1, o2;
  o1.x = f2bf(acc[0]); o1.y = f2bf(acc[1]); o1.z = f2bf(acc[2]); o1.w = f2bf(acc[3]);
  o2.x = f2bf(acc[4]); o2.y = f2bf(acc[5]); o2.z = f2bf(acc[6]); o2.w = f2bf(acc[7]);
  *(ushort4*)dst = o1;
  *(ushort4*)(dst + 4) = o2;
}

// ---------------- GEMM 128x128 (m97 structure) — narrow-N (fc2) ----------------
// EPI 2: +bias, f32 packed to ncols, only col<ncols.
template <int EPI>
__global__ __launch_bounds__(256, 2) void gemm_bt(
    const unsigned short* __restrict__ A, const unsigned short* __restrict__ Bt,
    const float* __restrict__ bias, float* __restrict__ Cf,
    unsigned short* __restrict__ Cb, int M, int N, int K, int ldc, int ncols) {
  __shared__ __align__(16) unsigned short Al[128 * 32];
  __shared__ __align__(16) unsigned short Bl[128 * 32];

  const int tid = threadIdx.x;
  const int wave = tid >> 6;
  const int lane = tid & 63;
  const int bm = blockIdx.y * 128;
  const int bn = blockIdx.x * 128;
  const int wr = (wave >> 1) * 64;
  const int wc = (wave & 1) * 64;

  f32x4 acc[4][4] = {};

  const int srow = tid >> 2;
  const int scol = (tid & 3) * 8;
  const unsigned short* Ag = A + (size_t)(bm + srow) * K + scol;
  const unsigned short* Bg = Bt + (size_t)(bn + srow) * K + scol;
  char* Alb = (char*)Al + wave * 1024;
  char* Blb = (char*)Bl + wave * 1024;

  const int fr = lane & 15;
  const int kq = lane >> 4;
  const unsigned short* Ard = Al + (wr + fr) * 32 + kq * 8;
  const unsigned short* Brd = Bl + (wc + fr) * 32 + kq * 8;

  for (int kt = 0; kt < K; kt += 32) {
    gload16(Ag + kt, Alb);
    gload16(Ag + kt + (size_t)64 * K, Alb + 4096);
    gload16(Bg + kt, Blb);
    gload16(Bg + kt + (size_t)64 * K, Blb + 4096);
    __syncthreads();
    bf16x8 af[4], bfr[4];
#pragma unroll
    for (int m = 0; m < 4; ++m) af[m] = *(const bf16x8*)(Ard + m * 16 * 32);
#pragma unroll
    for (int n = 0; n < 4; ++n) bfr[n] = *(const bf16x8*)(Brd + n * 16 * 32);
#pragma unroll
    for (int m = 0; m < 4; ++m)
#pragma unroll
      for (int n = 0; n < 4; ++n)
        acc[m][n] = __builtin_amdgcn_mfma_f32_16x16x32_bf16(af[m], bfr[n], acc[m][n], 0, 0, 0);
    __syncthreads();
  }

  const int fq = lane >> 4;
#pragma unroll
  for (int m = 0; m < 4; ++m) {
    const int row0 = bm + wr + m * 16 + fq * 4;
#pragma unroll
    for (int n = 0; n < 4; ++n) {
      const int col = bn + wc + n * 16 + fr;
#pragma unroll
      for (int r = 0; r < 4; ++r) {
        float v = acc[m][n][r];
        if constexpr (EPI == 2) {
          if (col < ncols) Cf[(size_t)(row0 + r) * ncols + col] = v + bias[col];
        } else {
          Cf[(size_t)(row0 + r) * ldc + col] = v;
        }
      }
    }
  }
}

// ---------------- GEMM 256x256, BK=64, 8-wave, 4-phase quadrant (round-2 core) ----------------
// EPI 0: f32 (ldc). EPI 1: +bias relu bf16 (ldc). EPI 2: plain bf16 (ldc).
template <int EPI>
__global__ __launch_bounds__(512, 1) void gemm256(
    const unsigned short* __restrict__ A, const unsigned short* __restrict__ Bt,
    const float* __restrict__ bias, float* __restrict__ Cf,
    unsigned short* __restrict__ Cb, int M, int N, int K, int ldc) {
  __shared__ __align__(16) unsigned short lds[2][2][256 * 64];  // [buf][A/B] 128 KiB

  const int tid = threadIdx.x;
  const int wid = tid >> 6;
  const int lane = tid & 63;
  const int wr = wid >> 2;      // 0..1  (M half)
  const int wc = wid & 3;       // 0..3  (N quarter)
  const int fr = lane & 15;
  const int kq = lane >> 4;

  // bijective XCD swizzle (m204)
  const int nx = gridDim.x;
  const int nwg = nx * gridDim.y;
  const int bid = blockIdx.y * nx + blockIdx.x;
  const int q = nwg >> 3, r8 = nwg & 7;
  const int xcd = bid & 7, idx = bid >> 3;
  const int wg = (xcd < r8 ? xcd * (q + 1) : r8 * (q + 1) + (xcd - r8) * q) + idx;
  const int bn = (wg % nx) * 256;
  const int bm = (wg / nx) * 256;

  const int NT = K >> 6;

  const int st_r = tid >> 3;
  const int st_x = (tid & 7) << 4;
  auto stage_half = [&](int buf, int mat, int half, int kt) {
    const unsigned short* src = mat ? Bt : A;
    const int gb = mat ? bn : bm;
#pragma unroll
    for (int iss = 0; iss < 2; ++iss) {
      const int row = half * 128 + iss * 64 + st_r;
      const int colb = st_x ^ ((row & 7) << 4);
      const unsigned short* g = src + (size_t)(gb + row) * K + kt * 64 + (colb >> 1);
      char* l = (char*)&lds[buf][mat][0] + (half * 2 + iss) * 8192 + (wid << 10);
      gload16(g, l);
    }
  };

  const int swz = (fr & 7) << 4;
  auto rdA = [&](int buf, int mh, int m, int kk) -> bf16x8 {
    const int row = wr * 128 + mh * 64 + m * 16 + fr;
    const int off = row * 128 + ((kk * 64 + kq * 16) ^ swz);
    return *(const bf16x8*)((const char*)&lds[buf][0][0] + off);
  };
  auto rdB = [&](int buf, int nh, int n, int kk) -> bf16x8 {
    const int row = wc * 64 + nh * 32 + n * 16 + fr;
    const int off = row * 128 + ((kk * 64 + kq * 16) ^ swz);
    return *(const bf16x8*)((const char*)&lds[buf][1][0] + off);
  };

  f32x4 acc[8][4] = {};
  bf16x8 a[4][2];
  bf16x8 b[2][2][2];

  // ---- prologue: K-tile 0 (all 4 halves) + K-tile 1 (B0, A0)
  stage_half(0, 1, 0, 0);
  stage_half(0, 0, 0, 0);
  stage_half(0, 1, 1, 0);
  stage_half(0, 0, 1, 0);
  if (NT > 1) {
    stage_half(1, 1, 0, 1);
    stage_half(1, 0, 0, 1);
    asm volatile("s_waitcnt vmcnt(4)" ::: "memory");
  } else {
    asm volatile("s_waitcnt vmcnt(0)" ::: "memory");
  }
  __builtin_amdgcn_sched_barrier(0);
  __builtin_amdgcn_s_barrier();

  for (int kt = 0; kt < NT; ++kt) {
    const int buf = kt & 1, nbuf = buf ^ 1;

    // ===== phase 0: quad (0,0) — reads A(mh0) + B(nh0); stage B1 of kt+1
#pragma unroll
    for (int m = 0; m < 4; ++m) {
      a[m][0] = rdA(buf, 0, m, 0);
      a[m][1] = rdA(buf, 0, m, 1);
    }
#pragma unroll
    for (int n = 0; n < 2; ++n) {
      b[0][n][0] = rdB(buf, 0, n, 0);
      b[0][n][1] = rdB(buf, 0, n, 1);
    }
    if (kt + 1 < NT) stage_half(nbuf, 1, 1, kt + 1);
    __builtin_amdgcn_s_barrier();
    asm volatile("s_waitcnt lgkmcnt(0)" ::: "memory");
    __builtin_amdgcn_sched_barrier(0);
    __builtin_amdgcn_s_setprio(1);
#pragma unroll
    for (int m = 0; m < 4; ++m)
#pragma unroll
      for (int n = 0; n < 2; ++n)
#pragma unroll
        for (int kk = 0; kk < 2; ++kk)
          acc[m][n] = __builtin_amdgcn_mfma_f32_16x16x32_bf16(a[m][kk], b[0][n][kk], acc[m][n], 0, 0, 0);
    __builtin_amdgcn_s_setprio(0);
    __builtin_amdgcn_sched_barrier(0);
    __builtin_amdgcn_s_barrier();

    // ===== phase 1: quad (0,1) — reads B(nh1); stage A1 of kt+1
#pragma unroll
    for (int n = 0; n < 2; ++n) {
      b[1][n][0] = rdB(buf, 1, n, 0);
      b[1][n][1] = rdB(buf, 1, n, 1);
    }
    if (kt + 1 < NT) stage_half(nbuf, 0, 1, kt + 1);
    __builtin_amdgcn_s_barrier();
    asm volatile("s_waitcnt lgkmcnt(0)" ::: "memory");
    __builtin_amdgcn_sched_barrier(0);
    __builtin_amdgcn_s_setprio(1);
#pragma unroll
    for (int m = 0; m < 4; ++m)
#pragma unroll
      for (int n = 0; n < 2; ++n)
#pragma unroll
        for (int kk = 0; kk < 2; ++kk)
          acc[m][n + 2] = __builtin_amdgcn_mfma_f32_16x16x32_bf16(a[m][kk], b[1][n][kk], acc[m][n + 2], 0, 0, 0);
    __builtin_amdgcn_s_setprio(0);
    __builtin_amdgcn_sched_barrier(0);
    __builtin_amdgcn_s_barrier();

    // ===== phase 2: quad (1,1) — reads A(mh1); stage B0 of kt+2 (current buf)
#pragma unroll
    for (int m = 0; m < 4; ++m) {
      a[m][0] = rdA(buf, 1, m, 0);
      a[m][1] = rdA(buf, 1, m, 1);
    }
    if (kt + 2 < NT) stage_half(buf, 1, 0, kt + 2);
    __builtin_amdgcn_s_barrier();
    asm volatile("s_waitcnt lgkmcnt(0)" ::: "memory");
    __builtin_amdgcn_sched_barrier(0);
    __builtin_amdgcn_s_setprio(1);
#pragma unroll
    for (int m = 0; m < 4; ++m)
#pragma unroll
      for (int n = 0; n < 2; ++n)
#pragma unroll
        for (int kk = 0; kk < 2; ++kk)
          acc[m + 4][n + 2] = __builtin_amdgcn_mfma_f32_16x16x32_bf16(a[m][kk], b[1][n][kk], acc[m + 4][n + 2], 0, 0, 0);
    __builtin_amdgcn_s_setprio(0);
    __builtin_amdgcn_sched_barrier(0);
    __builtin_amdgcn_s_barrier();

    // ===== phase 3: quad (1,0) — no reads; stage A0 of kt+2; counted vmcnt
    if (kt + 2 < NT) {
      stage_half(buf, 0, 0, kt + 2);
      asm volatile("s_waitcnt vmcnt(4)" ::: "memory");
    } else {
      asm volatile("s_waitcnt vmcnt(0)" ::: "memory");
    }
    __builtin_amdgcn_sched_barrier(0);
    __builtin_amdgcn_s_barrier();
    __builtin_amdgcn_s_setprio(1);
#pragma unroll
    for (int m = 0; m < 4; ++m)
#pragma unroll
      for (int n = 0; n < 2; ++n)
#pragma unroll
        for (int kk = 0; kk < 2; ++kk)
          acc[m + 4][n] = __builtin_amdgcn_mfma_f32_16x16x32_bf16(a[m][kk], b[0][n][kk], acc[m + 4][n], 0, 0, 0);
    __builtin_amdgcn_s_setprio(0);
    __builtin_amdgcn_sched_barrier(0);
    __builtin_amdgcn_s_barrier();
  }

  // ---- epilogue
  const int fq = lane >> 4;
#pragma unroll
  for (int m = 0; m < 8; ++m) {
    const int row0 = bm + wr * 128 + m * 16 + fq * 4;
#pragma unroll
    for (int n = 0; n < 4; ++n) {
      const int col = bn + wc * 64 + n * 16 + fr;
#pragma unroll
      for (int r = 0; r < 4; ++r) {
        float v = acc[m][n][r];
        if constexpr (EPI == 0) {
          Cf[(size_t)(row0 + r) * ldc + col] = v;
        } else if constexpr (EPI == 1) {
          v = fmaxf(v + bias[col], 0.0f);
          Cb[(size_t)(row0 + r) * ldc + col] = f2bf(v);
        } else {
          Cb[(size_t)(row0 + r) * ldc + col] = f2bf(v);
        }
      }
    }
  }
}

// ---------------- launch ----------------
extern "C" void kernel_launch(void* const* d_in, const int* in_sizes, int n_in,
                              void* d_out, int out_size, void* d_ws, size_t ws_size,
                              hipStream_t stream) {
  const float* enc  = (const float*)d_in[0];
  const float* mem  = (const float*)d_in[1];
  const float* fw1  = (const float*)d_in[2];
  const float* fb1  = (const float*)d_in[3];
  const float* fw2  = (const float*)d_in[4];
  const float* fb2  = (const float*)d_in[5];
  float* out = (float*)d_out;

  const int B = 4096, M = 8192, D = 2048, HID = 8192, OUT = 1000, OUTP = 1024;
  const int CAP = 1024;

  char* p = (char*)d_ws;
  auto alloc = [&](size_t bytes) {
    char* r = p;
    p += (bytes + 255) & ~(size_t)255;
    return r;
  };
  unsigned short* encN = (unsigned short*)alloc((size_t)B * D * 2);        // 16 MB
  unsigned short* memN = (unsigned short*)alloc((size_t)M * D * 2);        // 32 MB
  unsigned short* w1   = (unsigned short*)alloc((size_t)HID * 2 * D * 2);  // 64 MB
  unsigned short* w2   = (unsigned short*)alloc((size_t)OUTP * HID * 2);   // 16 MB
  unsigned short* sidx = (unsigned short*)alloc((size_t)B * CAP * 2);      // 8 MB
  unsigned short* swv  = (unsigned short*)alloc((size_t)B * CAP * 2);      // 8 MB
  int* scnt            = (int*)alloc((size_t)B * 4);                       // 16 KB
  unsigned short* simb = (unsigned short*)alloc((size_t)B * M * 2);        // 64 MB
  unsigned short* fin  = (unsigned short*)alloc((size_t)B * 2 * D * 2);    // 32 MB
  unsigned short* hid  = (unsigned short*)alloc((size_t)B * HID * 2);      // 64 MB

  rownorm_bf16<<<B, 256, 0, stream>>>(enc, encN, D);
  rownorm_bf16<<<M, 256, 0, stream>>>(mem, memN, D);
  convert_bf16<<<2048, 256, 0, stream>>>(fw1, w1, (long)HID * 2 * D / 4);
  convert_bf16<<<2048, 256, 0, stream>>>(fw2, w2, (long)OUT * HID / 4);
  // final_input cols [0,D): enc as bf16
  convert_strided_bf16<<<2048, 256, 0, stream>>>(enc, fin, B, D, 2 * D, 0);

  // sim = encN @ memN^T  [B, M] -> bf16
  gemm256<2><<<dim3(M / 256, B / 256), 512, 0, stream>>>(encN, memN, nullptr, nullptr, simb,
                                                         B, M, D, M);
  // sparsemax -> compact (idx, w) lists
  sparsemax_compact<<<B, 256, 0, stream>>>(simb, sidx, swv, scnt, M, CAP);
  // fin[:, D:2D) = sparse weights @ mem  (f32 gather-accumulate)
  mv_sparse<<<B, 256, 0, stream>>>(mem, sidx, swv, scnt, fin, D, 2 * D, CAP);
  // hidden = relu(final @ fc1_w^T + b1) -> bf16
  gemm256<1><<<dim3(HID / 256, B / 256), 512, 0, stream>>>(fin, w1, fb1, nullptr, hid,
                                                           B, HID, 2 * D, HID);
  // out = hidden @ fc2_w^T + b2 (only cols < 1000 stored)
  gemm_bt<2><<<dim3(OUTP / 128, B / 128), 256, 0, stream>>>(hid, w2, fb2, out, nullptr,
                                                            B, OUTP, HID, OUT, OUT);
}

// Round 5
// 948.875 us; speedup vs baseline: 1.3204x; 1.3204x over previous
//
#include <hip/hip_runtime.h>
#include <stdint.h>

typedef __attribute__((ext_vector_type(8))) __bf16 bf16x8;
typedef __attribute__((ext_vector_type(4))) float f32x4;

__device__ __forceinline__ unsigned short f2bf(float f) {
  unsigned u = __float_as_uint(f);
  u += 0x7FFFu + ((u >> 16) & 1u);
  return (unsigned short)(u >> 16);
}
__device__ __forceinline__ float bf2f(unsigned short u) {
  return __uint_as_float((unsigned)u << 16);
}

__device__ __forceinline__ void gload16(const void* g, void* lds) {
  __builtin_amdgcn_global_load_lds((const __attribute__((address_space(1))) void*)g,
                                   (__attribute__((address_space(3))) void*)lds, 16, 0, 0);
}

// ---------------- prep kernels ----------------

// one block per row: f32 row -> bf16 row (stride ldy) + rs[row] = 1/sqrt(sumsq+eps)
__global__ __launch_bounds__(256) void conv_norm_row(const float* __restrict__ x,
                                                     unsigned short* __restrict__ y,
                                                     float* __restrict__ rs,
                                                     int cols, int ldy) {
  const int row = blockIdx.x;
  const float4* x4 = (const float4*)(x + (size_t)row * cols);
  ushort4* y4 = (ushort4*)(y + (size_t)row * ldy);
  const int n4 = cols >> 2;
  float s = 0.f;
  for (int i = threadIdx.x; i < n4; i += 256) {
    float4 t = x4[i];
    s += t.x * t.x + t.y * t.y + t.z * t.z + t.w * t.w;
    ushort4 o;
    o.x = f2bf(t.x); o.y = f2bf(t.y); o.z = f2bf(t.z); o.w = f2bf(t.w);
    y4[i] = o;
  }
#pragma unroll
  for (int o = 32; o >= 1; o >>= 1) s += __shfl_xor(s, o, 64);
  __shared__ float red[4];
  if ((threadIdx.x & 63) == 0) red[threadIdx.x >> 6] = s;
  __syncthreads();
  if (threadIdx.x == 0) {
    const float tot = red[0] + red[1] + red[2] + red[3];
    rs[row] = 1.0f / sqrtf(tot + 1e-6f);
  }
}

__global__ __launch_bounds__(256) void convert_bf16(const float* __restrict__ x,
                                                    unsigned short* __restrict__ y,
                                                    long n4) {
  long i = (long)blockIdx.x * 256 + threadIdx.x;
  const long stride = (long)gridDim.x * 256;
  for (; i < n4; i += stride) {
    float4 t = ((const float4*)x)[i];
    ushort4 o;
    o.x = f2bf(t.x); o.y = f2bf(t.y); o.z = f2bf(t.z); o.w = f2bf(t.w);
    ((ushort4*)y)[i] = o;
  }
}

// x [R][C] f32 -> y [C][R] bf16
__global__ __launch_bounds__(256) void transpose_bf16(const float* __restrict__ x,
                                                      unsigned short* __restrict__ y,
                                                      int R, int C) {
  __shared__ float tile[64][65];
  const int r0 = blockIdx.y * 64;
  const int c0 = blockIdx.x * 64;
#pragma unroll
  for (int i = 0; i < 16; ++i) {
    int lin = i * 256 + threadIdx.x;
    int r = lin >> 6, c = lin & 63;
    tile[r][c] = x[(size_t)(r0 + r) * C + c0 + c];
  }
  __syncthreads();
#pragma unroll
  for (int i = 0; i < 16; ++i) {
    int lin = i * 256 + threadIdx.x;
    int tr = lin >> 6, tc = lin & 63;
    y[(size_t)(c0 + tr) * R + r0 + tc] = f2bf(tile[tc][tr]);
  }
}

// ---------------- sparsemax (scaled raw sims -> dense bf16 weights) ----------------
__global__ __launch_bounds__(256) void sparsemax_scaled(
    const unsigned short* __restrict__ simb, const float* __restrict__ rs,
    const float* __restrict__ cs, unsigned short* __restrict__ w, int Mc) {
  const int row = blockIdx.x;
  const int tid = threadIdx.x;
  const float r = rs[row];
  const ushort4* z4 = (const ushort4*)(simb + (size_t)row * Mc);
  const float4* c4 = (const float4*)cs;
  float z[32];
#pragma unroll
  for (int i = 0; i < 8; ++i) {
    ushort4 v = z4[i * 256 + tid];
    float4 c = c4[i * 256 + tid];
    z[i * 4 + 0] = bf2f(v.x) * r * c.x;
    z[i * 4 + 1] = bf2f(v.y) * r * c.y;
    z[i * 4 + 2] = bf2f(v.z) * r * c.z;
    z[i * 4 + 3] = bf2f(v.w) * r * c.w;
  }
  float mx = z[0];
#pragma unroll
  for (int j = 1; j < 32; ++j) mx = fmaxf(mx, z[j]);
#pragma unroll
  for (int o = 32; o >= 1; o >>= 1) mx = fmaxf(mx, __shfl_xor(mx, o, 64));
  __shared__ float red[4];
  const int wv = tid >> 6, ln = tid & 63;
  if (ln == 0) red[wv] = mx;
  __syncthreads();
  mx = fmaxf(fmaxf(red[0], red[1]), fmaxf(red[2], red[3]));

  float lo = mx - 1.0f, hi = mx;
  for (int it = 0; it < 32; ++it) {
    const float tau = 0.5f * (lo + hi);
    float s = 0.f;
#pragma unroll
    for (int j = 0; j < 32; ++j) s += fmaxf(z[j] - tau, 0.f);
#pragma unroll
    for (int o = 32; o >= 1; o >>= 1) s += __shfl_xor(s, o, 64);
    __syncthreads();
    if (ln == 0) red[wv] = s;
    __syncthreads();
    s = red[0] + red[1] + red[2] + red[3];
    if (s > 1.0f) lo = tau; else hi = tau;
  }
  const float tau = 0.5f * (lo + hi);
  unsigned short* wrow = w + (size_t)row * Mc;
#pragma unroll
  for (int i = 0; i < 8; ++i) {
    ushort4 o;
    o.x = f2bf(fmaxf(z[i * 4 + 0] - tau, 0.f));
    o.y = f2bf(fmaxf(z[i * 4 + 1] - tau, 0.f));
    o.z = f2bf(fmaxf(z[i * 4 + 2] - tau, 0.f));
    o.w = f2bf(fmaxf(z[i * 4 + 3] - tau, 0.f));
    ((ushort4*)wrow)[i * 256 + tid] = o;
  }
}

// ---------------- GEMM 128x128 (m97 structure) ----------------
// EPI 2: +bias, f32 packed ncols (col<ncols). EPI 3: plain bf16 (ldc).
template <int EPI>
__global__ __launch_bounds__(256, 2) void gemm_bt(
    const unsigned short* __restrict__ A, const unsigned short* __restrict__ Bt,
    const float* __restrict__ bias, float* __restrict__ Cf,
    unsigned short* __restrict__ Cb, int M, int N, int K, int ldc, int ncols) {
  __shared__ __align__(16) unsigned short Al[128 * 32];
  __shared__ __align__(16) unsigned short Bl[128 * 32];

  const int tid = threadIdx.x;
  const int wave = tid >> 6;
  const int lane = tid & 63;
  const int bm = blockIdx.y * 128;
  const int bn = blockIdx.x * 128;
  const int wr = (wave >> 1) * 64;
  const int wc = (wave & 1) * 64;

  f32x4 acc[4][4] = {};

  const int srow = tid >> 2;
  const int scol = (tid & 3) * 8;
  const unsigned short* Ag = A + (size_t)(bm + srow) * K + scol;
  const unsigned short* Bg = Bt + (size_t)(bn + srow) * K + scol;
  char* Alb = (char*)Al + wave * 1024;
  char* Blb = (char*)Bl + wave * 1024;

  const int fr = lane & 15;
  const int kq = lane >> 4;
  const unsigned short* Ard = Al + (wr + fr) * 32 + kq * 8;
  const unsigned short* Brd = Bl + (wc + fr) * 32 + kq * 8;

  for (int kt = 0; kt < K; kt += 32) {
    gload16(Ag + kt, Alb);
    gload16(Ag + kt + (size_t)64 * K, Alb + 4096);
    gload16(Bg + kt, Blb);
    gload16(Bg + kt + (size_t)64 * K, Blb + 4096);
    __syncthreads();
    bf16x8 af[4], bfr[4];
#pragma unroll
    for (int m = 0; m < 4; ++m) af[m] = *(const bf16x8*)(Ard + m * 16 * 32);
#pragma unroll
    for (int n = 0; n < 4; ++n) bfr[n] = *(const bf16x8*)(Brd + n * 16 * 32);
#pragma unroll
    for (int m = 0; m < 4; ++m)
#pragma unroll
      for (int n = 0; n < 4; ++n)
        acc[m][n] = __builtin_amdgcn_mfma_f32_16x16x32_bf16(af[m], bfr[n], acc[m][n], 0, 0, 0);
    __syncthreads();
  }

  const int fq = lane >> 4;
#pragma unroll
  for (int m = 0; m < 4; ++m) {
    const int row0 = bm + wr + m * 16 + fq * 4;
#pragma unroll
    for (int n = 0; n < 4; ++n) {
      const int col = bn + wc + n * 16 + fr;
#pragma unroll
      for (int r = 0; r < 4; ++r) {
        float v = acc[m][n][r];
        if constexpr (EPI == 2) {
          if (col < ncols) Cf[(size_t)(row0 + r) * ncols + col] = v + bias[col];
        } else {
          Cb[(size_t)(row0 + r) * ldc + col] = f2bf(v);
        }
      }
    }
  }
}

// ---------------- GEMM 256x256, BK=64, 8-wave, 4-phase + cross-phase reads ----------
// C[M,N] = A[M,K](row stride lda) * Bt[N,K]^T. bf16 in, f32 acc.
// Round-2 skeleton (stages/barriers/vmcnt identical); ds_reads moved >=1 phase
// ahead of their consuming MFMA so every lgkmcnt(0) is a steady-state no-op:
//   prologue reads A0,B0(kt0); ph0 MFMA(q00)+read B1; ph1 MFMA(q01)+read A1;
//   ph2 MFMA(q11); ph3 MFMA(q10)+prefetch A0,B0(kt+1) from nbuf.
// EPI 1: +bias relu bf16 (ldc). EPI 2: plain bf16 (ldc).
template <int EPI>
__global__ __launch_bounds__(512, 1) void gemm256(
    const unsigned short* __restrict__ A, const unsigned short* __restrict__ Bt,
    const float* __restrict__ bias, float* __restrict__ Cf,
    unsigned short* __restrict__ Cb, int M, int N, int K, int lda, int ldc) {
  __shared__ __align__(16) unsigned short lds[2][2][256 * 64];  // 128 KiB

  const int tid = threadIdx.x;
  const int wid = tid >> 6;
  const int lane = tid & 63;
  const int wr = wid >> 2;      // 0..1  (128-row band)
  const int wc = wid & 3;       // 0..3  (64-col band)
  const int fr = lane & 15;
  const int kq = lane >> 4;

  // bijective XCD swizzle (m204)
  const int nx = gridDim.x;
  const int nwg = nx * gridDim.y;
  const int bid = blockIdx.y * nx + blockIdx.x;
  const int q = nwg >> 3, r8 = nwg & 7;
  const int xcd = bid & 7, idx = bid >> 3;
  const int wg = (xcd < r8 ? xcd * (q + 1) : r8 * (q + 1) + (xcd - r8) * q) + idx;
  const int bn = (wg % nx) * 256;
  const int bm = (wg / nx) * 256;

  const int NT = K >> 6;

  const int st_r = tid >> 3;
  const int st_x = (tid & 7) << 4;
  auto stage_half = [&](int buf, int mat, int half, int kt) {
    const unsigned short* src = mat ? Bt : A;
    const int gb = mat ? bn : bm;
    const int ld = mat ? K : lda;
#pragma unroll
    for (int iss = 0; iss < 2; ++iss) {
      const int row = half * 128 + iss * 64 + st_r;
      const int colb = st_x ^ ((row & 7) << 4);
      const unsigned short* g = src + (size_t)(gb + row) * ld + kt * 64 + (colb >> 1);
      char* l = (char*)&lds[buf][mat][0] + (half * 2 + iss) * 8192 + (wid << 10);
      gload16(g, l);
    }
  };

  const int swz = (fr & 7) << 4;
  auto rdA = [&](int buf, int mh, int m, int kk) -> bf16x8 {
    const int row = wr * 128 + mh * 64 + m * 16 + fr;
    const int off = row * 128 + ((kk * 64 + kq * 16) ^ swz);
    return *(const bf16x8*)((const char*)&lds[buf][0][0] + off);
  };
  auto rdB = [&](int buf, int nh, int n, int kk) -> bf16x8 {
    const int row = wc * 64 + nh * 32 + n * 16 + fr;
    const int off = row * 128 + ((kk * 64 + kq * 16) ^ swz);
    return *(const bf16x8*)((const char*)&lds[buf][1][0] + off);
  };

  f32x4 acc[8][4] = {};
  bf16x8 a[4][2];    // current A half (A0 in ph0-1, A1 in ph2-3, next-A0 after ph3)
  bf16x8 b0[2][2];   // B half 0 (ph0, ph3; next-B0 prefetched at ph3)
  bf16x8 b1[2][2];   // B half 1 (ph1, ph2)

  // ---- prologue: K-tile 0 (4 halves) + K-tile 1 (B0, A0); then read A0,B0(kt0)
  stage_half(0, 1, 0, 0);
  stage_half(0, 0, 0, 0);
  stage_half(0, 1, 1, 0);
  stage_half(0, 0, 1, 0);
  if (NT > 1) {
    stage_half(1, 1, 0, 1);
    stage_half(1, 0, 0, 1);
    asm volatile("s_waitcnt vmcnt(4)" ::: "memory");
  } else {
    asm volatile("s_waitcnt vmcnt(0)" ::: "memory");
  }
  __builtin_amdgcn_sched_barrier(0);
  __builtin_amdgcn_s_barrier();
#pragma unroll
  for (int m = 0; m < 4; ++m) {
    a[m][0] = rdA(0, 0, m, 0);
    a[m][1] = rdA(0, 0, m, 1);
  }
#pragma unroll
  for (int n = 0; n < 2; ++n) {
    b0[n][0] = rdB(0, 0, n, 0);
    b0[n][1] = rdB(0, 0, n, 1);
  }

  for (int kt = 0; kt < NT; ++kt) {
    const int buf = kt & 1, nbuf = buf ^ 1;

    // ===== ph0: MFMA quad(0,0) [a=A0, b0]; stage B1(kt+1); post-read b1
    if (kt + 1 < NT) stage_half(nbuf, 1, 1, kt + 1);
    __builtin_amdgcn_s_barrier();
    asm volatile("s_waitcnt lgkmcnt(0)" ::: "memory");
    __builtin_amdgcn_sched_barrier(0);
    __builtin_amdgcn_s_setprio(1);
#pragma unroll
    for (int m = 0; m < 4; ++m)
#pragma unroll
      for (int n = 0; n < 2; ++n)
#pragma unroll
        for (int kk = 0; kk < 2; ++kk)
          acc[m][n] = __builtin_amdgcn_mfma_f32_16x16x32_bf16(a[m][kk], b0[n][kk], acc[m][n], 0, 0, 0);
    __builtin_amdgcn_s_setprio(0);
    __builtin_amdgcn_sched_barrier(0);
#pragma unroll
    for (int n = 0; n < 2; ++n) {
      b1[n][0] = rdB(buf, 1, n, 0);
      b1[n][1] = rdB(buf, 1, n, 1);
    }
    __builtin_amdgcn_s_barrier();

    // ===== ph1: MFMA quad(0,1) [a=A0, b1]; stage A1(kt+1); post-read a<-A1
    if (kt + 1 < NT) stage_half(nbuf, 0, 1, kt + 1);
    __builtin_amdgcn_s_barrier();
    asm volatile("s_waitcnt lgkmcnt(0)" ::: "memory");
    __builtin_amdgcn_sched_barrier(0);
    __builtin_amdgcn_s_setprio(1);
#pragma unroll
    for (int m = 0; m < 4; ++m)
#pragma unroll
      for (int n = 0; n < 2; ++n)
#pragma unroll
        for (int kk = 0; kk < 2; ++kk)
          acc[m][n + 2] = __builtin_amdgcn_mfma_f32_16x16x32_bf16(a[m][kk], b1[n][kk], acc[m][n + 2], 0, 0, 0);
    __builtin_amdgcn_s_setprio(0);
    __builtin_amdgcn_sched_barrier(0);
#pragma unroll
    for (int m = 0; m < 4; ++m) {
      a[m][0] = rdA(buf, 1, m, 0);
      a[m][1] = rdA(buf, 1, m, 1);
    }
    __builtin_amdgcn_s_barrier();

    // ===== ph2: MFMA quad(1,1) [a=A1, b1]; stage B0(kt+2, buf); no reads
    if (kt + 2 < NT) stage_half(buf, 1, 0, kt + 2);
    __builtin_amdgcn_s_barrier();
    asm volatile("s_waitcnt lgkmcnt(0)" ::: "memory");
    __builtin_amdgcn_sched_barrier(0);
    __builtin_amdgcn_s_setprio(1);
#pragma unroll
    for (int m = 0; m < 4; ++m)
#pragma unroll
      for (int n = 0; n < 2; ++n)
#pragma unroll
        for (int kk = 0; kk < 2; ++kk)
          acc[m + 4][n + 2] = __builtin_amdgcn_mfma_f32_16x16x32_bf16(a[m][kk], b1[n][kk], acc[m + 4][n + 2], 0, 0, 0);
    __builtin_amdgcn_s_setprio(0);
    __builtin_amdgcn_sched_barrier(0);
    __builtin_amdgcn_s_barrier();

    // ===== ph3: stage A0(kt+2, buf); vmcnt(4); MFMA quad(1,0) [a=A1, b0];
    //            post-read prefetch a<-A0(kt+1,nbuf), b0<-B0(kt+1,nbuf)
    if (kt + 2 < NT) {
      stage_half(buf, 0, 0, kt + 2);
      asm volatile("s_waitcnt vmcnt(4)" ::: "memory");
    } else {
      asm volatile("s_waitcnt vmcnt(0)" ::: "memory");
    }
    __builtin_amdgcn_sched_barrier(0);
    __builtin_amdgcn_s_barrier();
    asm volatile("s_waitcnt lgkmcnt(0)" ::: "memory");
    __builtin_amdgcn_sched_barrier(0);
    __builtin_amdgcn_s_setprio(1);
#pragma unroll
    for (int m = 0; m < 4; ++m)
#pragma unroll
      for (int n = 0; n < 2; ++n)
#pragma unroll
        for (int kk = 0; kk < 2; ++kk)
          acc[m + 4][n] = __builtin_amdgcn_mfma_f32_16x16x32_bf16(a[m][kk], b0[n][kk], acc[m + 4][n], 0, 0, 0);
    __builtin_amdgcn_s_setprio(0);
    __builtin_amdgcn_sched_barrier(0);
    if (kt + 1 < NT) {
#pragma unroll
      for (int m = 0; m < 4; ++m) {
        a[m][0] = rdA(nbuf, 0, m, 0);
        a[m][1] = rdA(nbuf, 0, m, 1);
      }
#pragma unroll
      for (int n = 0; n < 2; ++n) {
        b0[n][0] = rdB(nbuf, 0, n, 0);
        b0[n][1] = rdB(nbuf, 0, n, 1);
      }
    }
    __builtin_amdgcn_s_barrier();
  }

  // ---- epilogue
  const int fq = lane >> 4;
#pragma unroll
  for (int m = 0; m < 8; ++m) {
    const int row0 = bm + wr * 128 + m * 16 + fq * 4;
#pragma unroll
    for (int n = 0; n < 4; ++n) {
      const int col = bn + wc * 64 + n * 16 + fr;
#pragma unroll
      for (int r = 0; r < 4; ++r) {
        float v = acc[m][n][r];
        if constexpr (EPI == 1) {
          v = fmaxf(v + bias[col], 0.0f);
          Cb[(size_t)(row0 + r) * ldc + col] = f2bf(v);
        } else {
          Cb[(size_t)(row0 + r) * ldc + col] = f2bf(v);
        }
      }
    }
  }
}

// ---------------- launch ----------------
extern "C" void kernel_launch(void* const* d_in, const int* in_sizes, int n_in,
                              void* d_out, int out_size, void* d_ws, size_t ws_size,
                              hipStream_t stream) {
  const float* enc  = (const float*)d_in[0];
  const float* mem  = (const float*)d_in[1];
  const float* fw1  = (const float*)d_in[2];
  const float* fb1  = (const float*)d_in[3];
  const float* fw2  = (const float*)d_in[4];
  const float* fb2  = (const float*)d_in[5];
  float* out = (float*)d_out;

  const int B = 4096, M = 8192, D = 2048, HID = 8192, OUT = 1000, OUTP = 1024;

  char* p = (char*)d_ws;
  auto alloc = [&](size_t bytes) {
    char* r = p;
    p += (bytes + 255) & ~(size_t)255;
    return r;
  };
  unsigned short* memB = (unsigned short*)alloc((size_t)M * D * 2);        // 32 MB raw bf16
  unsigned short* memT = (unsigned short*)alloc((size_t)D * M * 2);        // 32 MB raw^T bf16
  unsigned short* w1   = (unsigned short*)alloc((size_t)HID * 2 * D * 2);  // 64 MB
  unsigned short* w2   = (unsigned short*)alloc((size_t)OUTP * HID * 2);   // 16 MB
  unsigned short* wts  = (unsigned short*)alloc((size_t)B * M * 2);        // 64 MB
  unsigned short* fin  = (unsigned short*)alloc((size_t)B * 2 * D * 2);    // 32 MB
  float* rs            = (float*)alloc((size_t)B * 4);
  float* cs            = (float*)alloc((size_t)M * 4);
  unsigned short* hid  = (unsigned short*)alloc((size_t)B * HID * 2);      // 64 MB
  unsigned short* simb = hid;  // alias: simb dead before fc1 writes hid

  // prep: raw bf16 casts + norms + mem transpose
  conv_norm_row<<<B, 256, 0, stream>>>(enc, fin, rs, D, 2 * D);   // fin left half + enc norms
  conv_norm_row<<<M, 256, 0, stream>>>(mem, memB, cs, D, D);      // raw bf16 mem + mem norms
  transpose_bf16<<<dim3(D / 64, M / 64), 256, 0, stream>>>(mem, memT, M, D);
  convert_bf16<<<2048, 256, 0, stream>>>(fw1, w1, (long)HID * 2 * D / 4);
  convert_bf16<<<2048, 256, 0, stream>>>(fw2, w2, (long)OUT * HID / 4);

  // raw sims = bf16(enc) @ bf16(mem)^T  [B, M] -> bf16 (norm scales folded into sparsemax)
  gemm256<2><<<dim3(M / 256, B / 256), 512, 0, stream>>>(fin, memB, nullptr, nullptr, simb,
                                                         B, M, D, 2 * D, M);
  // sparsemax(z * rs * cs) -> dense bf16 weights
  sparsemax_scaled<<<B, 256, 0, stream>>>(simb, rs, cs, wts, M);
  // fin[:, D:2D) = wts @ mem   (dense, fused bf16 store)
  gemm_bt<3><<<dim3(D / 128, B / 128), 256, 0, stream>>>(wts, memT, nullptr, nullptr, fin + D,
                                                         B, D, M, 2 * D, 0);
  // hidden = relu(fin @ fc1_w^T + b1) -> bf16
  gemm256<1><<<dim3(HID / 256, B / 256), 512, 0, stream>>>(fin, w1, fb1, nullptr, hid,
                                                           B, HID, 2 * D, 2 * D, HID);
  // out = hidden @ fc2_w^T + b2 (only cols < 1000 stored)
  gemm_bt<2><<<dim3(OUTP / 128, B / 128), 256, 0, stream>>>(hid, w2, fb2, out, nullptr,
                                                            B, OUTP, HID, OUT, OUT);
}